// Round 14
// baseline (438.190 us; speedup 1.0000x reference)
//
#include <hip/hip_runtime.h>

#define HD 64      // hidden dim D
#define NBLD 1024  // build blocks: 4/CU co-resident (2x margin), all CUs busy

typedef short  bf16x8 __attribute__((ext_vector_type(8)));
typedef float  f32x4  __attribute__((ext_vector_type(4)));

__device__ inline float bf2f(ushort u) {
    unsigned x = ((unsigned)u) << 16;
    return __builtin_bit_cast(float, x);
}
__device__ inline ushort f2bf(float f) {   // round-to-nearest-even
    unsigned u = __builtin_bit_cast(unsigned, f);
    u += 0x7fffu + ((u >> 16) & 1u);
    return (ushort)(u >> 16);
}

// ---- fused prep: f2bf(x) | f2bf(W) | zero deg | zero barrier slots ----
__global__ void prep_kernel(const float4* __restrict__ x, ushort4* __restrict__ hb, int xn4,
                            const float4* __restrict__ W, ushort4* __restrict__ Wb, int wn4,
                            int4* __restrict__ deg4, int dn4, int4* __restrict__ bar4) {
    int i = blockIdx.x * blockDim.x + threadIdx.x;
    if (i < xn4) {
        float4 v = x[i];
        ushort4 o; o.x = f2bf(v.x); o.y = f2bf(v.y); o.z = f2bf(v.z); o.w = f2bf(v.w);
        hb[i] = o;
        return;
    }
    int j = i - xn4;
    if (j < wn4) {
        float4 v = W[j];
        ushort4 o; o.x = f2bf(v.x); o.y = f2bf(v.y); o.z = f2bf(v.z); o.w = f2bf(v.w);
        Wb[j] = o;
        return;
    }
    int k = j - wn4;
    if (k < dn4) { deg4[k] = int4{0, 0, 0, 0}; return; }
    int m = k - dn4;
    if (m < 4) bar4[m] = int4{0, 0, 0, 0};
}

// device-scope grid barrier for NBLD co-resident blocks; fresh slot per use,
// slots zeroed by prep each launch (replay-deterministic). Proven round 13.
__device__ inline void gridbar(int* bar, int slot) {
    __syncthreads();
    if (threadIdx.x == 0) {
        __threadfence();
        atomicAdd(&bar[slot], 1);
        while (__hip_atomic_load(&bar[slot], __ATOMIC_ACQUIRE,
                                 __HIP_MEMORY_SCOPE_AGENT) < NBLD) {}
    }
    __syncthreads();
}

// ---- single-launch CSR build at full parallelism (round-13 fix: 64 -> 1024 blocks)
// phases: histogram | chunk-scan (1024 elems/block) | apply | fill
// hist/fill dst-range partitioned: 8 slices x 128 blocks, XCD-local atomic lines.
__global__ __launch_bounds__(256, 4) void build_kernel(
    const int* __restrict__ esrc, const int* __restrict__ edst,
    int* __restrict__ deg, int* __restrict__ bsum,
    int* __restrict__ row_start, int* __restrict__ cursor,
    float* __restrict__ inv_deg, int* __restrict__ csr,
    int* __restrict__ bar, int N, int E, int NBsc) {
    const int tid = threadIdx.x, lane = tid & 63, wid = tid >> 6;
    const int per = (N + 7) / 8;

    {   // phase 1: degree histogram
        const int g = blockIdx.x & 7;
        const int lo = g * per;
        const int hi = min(N, lo + per);
        const int b = blockIdx.x >> 3;
        for (int e = b * 256 + tid; e < E; e += (NBLD >> 3) * 256) {
            int d = edst[e];
            if (d >= lo && d < hi) atomicAdd(&deg[d], 1);
        }
    }
    gridbar(bar, 0);

    __shared__ int wtot[4], woff[4];
    if ((int)blockIdx.x < NBsc) {   // phase 2: local excl scan, 1024 elems/block, 4/thread
        int i0 = blockIdx.x * 1024 + tid * 4;
        int d0 = (i0 + 0 < N) ? deg[i0 + 0] : 0;
        int d1 = (i0 + 1 < N) ? deg[i0 + 1] : 0;
        int d2 = (i0 + 2 < N) ? deg[i0 + 2] : 0;
        int d3 = (i0 + 3 < N) ? deg[i0 + 3] : 0;
        int tsum = d0 + d1 + d2 + d3;
        int s = tsum;
#pragma unroll
        for (int off = 1; off < 64; off <<= 1) {
            int t = __shfl_up(s, off, 64);
            if (lane >= off) s += t;
        }
        if (lane == 63) wtot[wid] = s;
        __syncthreads();
        if (wid == 0 && lane < 4) {
            int t = wtot[lane];
            int ss = t;
#pragma unroll
            for (int off = 1; off < 4; off <<= 1) {
                int u = __shfl_up(ss, off, 64);
                if (lane >= off) ss += u;
            }
            woff[lane] = ss - t;
            if (lane == 3) bsum[blockIdx.x] = ss;   // block total
        }
        __syncthreads();
        int base = woff[wid] + (s - tsum);
        if (i0 + 0 < N) row_start[i0 + 0] = base;
        if (i0 + 1 < N) row_start[i0 + 1] = base + d0;
        if (i0 + 2 < N) row_start[i0 + 2] = base + d0 + d1;
        if (i0 + 3 < N) row_start[i0 + 3] = base + d0 + d1 + d2;
    }
    gridbar(bar, 1);

    if ((int)blockIdx.x < NBsc) {   // phase 3: apply chunk offset (NBsc <= 64: one wave)
        __shared__ int boff_s;
        if (tid < 64) {
            int v = (lane < NBsc) ? bsum[lane] : 0;
            int s = v;
#pragma unroll
            for (int off = 1; off < 64; off <<= 1) {
                int t = __shfl_up(s, off, 64);
                if (lane >= off) s += t;
            }
            if (lane == (int)blockIdx.x) boff_s = s - v;
        }
        __syncthreads();
        const int boff = boff_s;
        int i0 = blockIdx.x * 1024 + tid * 4;
#pragma unroll
        for (int q = 0; q < 4; ++q) {
            int i = i0 + q;
            if (i < N) {
                int e = row_start[i] + boff;
                row_start[i] = e;
                cursor[i] = e;
                int d = deg[i];
                inv_deg[i] = (d > 0) ? 1.0f / (float)d : 0.0f;
            }
        }
        if (blockIdx.x == 0 && tid == 0) row_start[N] = E;
    }
    gridbar(bar, 2);

    {   // phase 4: CSR fill
        const int g = blockIdx.x & 7;
        const int lo = g * per;
        const int hi = min(N, lo + per);
        const int b = blockIdx.x >> 3;
        for (int e = b * 256 + tid; e < E; e += (NBLD >> 3) * 256) {
            int d = edst[e];
            if (d >= lo && d < hi) {
                int p = atomicAdd(&cursor[d], 1);
                csr[p] = esrc[e];
            }
        }
    }
}

// ---- aggregate (round-10 proven): wave per node, 4 lane-groups x 16 lanes,
// ushort4/lane; 16-neighbor inner step = 4 loads in flight per lane ----
__global__ __launch_bounds__(256, 8) void agg_kernel(
    const ushort* __restrict__ hb, const int* __restrict__ row_start,
    const int* __restrict__ csr, const float* __restrict__ inv_deg,
    ushort* __restrict__ neighb, int N) {
    const int wv = (blockIdx.x * blockDim.x + threadIdx.x) >> 6;
    const int lane = threadIdx.x & 63;
    if (wv >= N) return;
    const int rs = row_start[wv];
    const int re = row_start[wv + 1];
    const int grp = lane >> 4;
    const int sub = (lane & 15) << 2;

    float a0 = 0.f, a1 = 0.f, a2 = 0.f, a3 = 0.f;
    float b0 = 0.f, b1 = 0.f, b2 = 0.f, b3 = 0.f;
    float c0 = 0.f, c1 = 0.f, c2 = 0.f, c3 = 0.f;
    float d0 = 0.f, d1 = 0.f, d2 = 0.f, d3 = 0.f;
    int j = rs;
    while (j < re) {
        int take = re - j;
        if (take > 64) take = 64;
        int idx = (lane < take) ? csr[j + lane] : 0;
        int i = 0;
        for (; i + 16 <= take; i += 16) {
            int s0 = __shfl(idx, i + grp, 64);
            int s1 = __shfl(idx, i + 4 + grp, 64);
            int s2 = __shfl(idx, i + 8 + grp, 64);
            int s3 = __shfl(idx, i + 12 + grp, 64);
            ushort4 v0 = *(const ushort4*)&hb[(s0 << 6) + sub];
            ushort4 v1 = *(const ushort4*)&hb[(s1 << 6) + sub];
            ushort4 v2 = *(const ushort4*)&hb[(s2 << 6) + sub];
            ushort4 v3 = *(const ushort4*)&hb[(s3 << 6) + sub];
            a0 += bf2f(v0.x); a1 += bf2f(v0.y); a2 += bf2f(v0.z); a3 += bf2f(v0.w);
            b0 += bf2f(v1.x); b1 += bf2f(v1.y); b2 += bf2f(v1.z); b3 += bf2f(v1.w);
            c0 += bf2f(v2.x); c1 += bf2f(v2.y); c2 += bf2f(v2.z); c3 += bf2f(v2.w);
            d0 += bf2f(v3.x); d1 += bf2f(v3.y); d2 += bf2f(v3.z); d3 += bf2f(v3.w);
        }
        for (; i + 8 <= take; i += 8) {
            int s0 = __shfl(idx, i + grp, 64);
            int s1 = __shfl(idx, i + 4 + grp, 64);
            ushort4 v0 = *(const ushort4*)&hb[(s0 << 6) + sub];
            ushort4 v1 = *(const ushort4*)&hb[(s1 << 6) + sub];
            a0 += bf2f(v0.x); a1 += bf2f(v0.y); a2 += bf2f(v0.z); a3 += bf2f(v0.w);
            b0 += bf2f(v1.x); b1 += bf2f(v1.y); b2 += bf2f(v1.z); b3 += bf2f(v1.w);
        }
        for (; i < take; i += 4) {
            int p = i + grp;
            int s = __shfl(idx, p < take ? p : 0, 64);
            if (p < take) {
                ushort4 v = *(const ushort4*)&hb[(s << 6) + sub];
                a0 += bf2f(v.x); a1 += bf2f(v.y); a2 += bf2f(v.z); a3 += bf2f(v.w);
            }
        }
        j += take;
    }
    a0 += b0 + c0 + d0; a1 += b1 + c1 + d1;
    a2 += b2 + c2 + d2; a3 += b3 + c3 + d3;
    a0 += __shfl_xor(a0, 16, 64); a0 += __shfl_xor(a0, 32, 64);
    a1 += __shfl_xor(a1, 16, 64); a1 += __shfl_xor(a1, 32, 64);
    a2 += __shfl_xor(a2, 16, 64); a2 += __shfl_xor(a2, 32, 64);
    a3 += __shfl_xor(a3, 16, 64); a3 += __shfl_xor(a3, 32, 64);
    if (grp == 0) {
        float inv = inv_deg[wv];
        ushort4 o;
        o.x = f2bf(a0 * inv); o.y = f2bf(a1 * inv);
        o.z = f2bf(a2 * inv); o.w = f2bf(a3 * inv);
        *(ushort4*)&neighb[(wv << 6) + sub] = o;
    }
}

// ---- MFMA GEMM + relu + L2-norm (round-9 proven) ----
__global__ __launch_bounds__(256) void gemm_mfma_kernel(
    const ushort* __restrict__ hb, const ushort* __restrict__ nbf,
    const ushort* __restrict__ Wb, float* __restrict__ out,
    ushort* __restrict__ hb_out, int N, int last) {
    const int lane = threadIdx.x & 63;
    const int w = threadIdx.x >> 6;
    const int base = blockIdx.x * 64 + w * 16;
    const int m = lane & 15;
    const int kq = lane >> 4;
    int anode = base + m;
    if (anode > N - 1) anode = N - 1;
    const long long arow = (long long)anode * HD;

    f32x4 acc[4] = {{0.f,0.f,0.f,0.f},{0.f,0.f,0.f,0.f},{0.f,0.f,0.f,0.f},{0.f,0.f,0.f,0.f}};
#pragma unroll
    for (int kk = 0; kk < 4; ++kk) {
        const ushort* ap = (kk < 2 ? hb : nbf) + arow + (kk & 1) * 32 + kq * 8;
        bf16x8 a = *(const bf16x8*)ap;
        const ushort* bp = Wb + (long long)m * 128 + kk * 32 + kq * 8;
#pragma unroll
        for (int t = 0; t < 4; ++t) {
            bf16x8 b = *(const bf16x8*)(bp + (long long)t * 16 * 128);
            acc[t] = __builtin_amdgcn_mfma_f32_16x16x32_bf16(a, b, acc[t], 0, 0, 0);
        }
    }

    float sq[4] = {0.f, 0.f, 0.f, 0.f};
#pragma unroll
    for (int t = 0; t < 4; ++t)
#pragma unroll
        for (int r = 0; r < 4; ++r) {
            float v = fmaxf(acc[t][r], 0.f);
            acc[t][r] = v;
            sq[r] += v * v;
        }
#pragma unroll
    for (int off = 1; off < 16; off <<= 1)
#pragma unroll
        for (int r = 0; r < 4; ++r) sq[r] += __shfl_xor(sq[r], off, 64);

    float scl[4];
#pragma unroll
    for (int r = 0; r < 4; ++r) scl[r] = 1.f / fmaxf(sqrtf(sq[r]), 1e-12f);

    if (last) {
#pragma unroll
        for (int r = 0; r < 4; ++r) {
            int node = base + kq * 4 + r;
            if (node < N) {
#pragma unroll
                for (int t = 0; t < 4; ++t)
                    out[(long long)node * HD + t * 16 + m] = acc[t][r] * scl[r];
            }
        }
    } else {
#pragma unroll
        for (int r = 0; r < 4; ++r) {
            int node = base + kq * 4 + r;
            if (node < N) {
#pragma unroll
                for (int t = 0; t < 4; ++t)
                    hb_out[(long long)node * HD + t * 16 + m] = f2bf(acc[t][r] * scl[r]);
            }
        }
    }
}

extern "C" void kernel_launch(void* const* d_in, const int* in_sizes, int n_in,
                              void* d_out, int out_size, void* d_ws, size_t ws_size,
                              hipStream_t stream) {
    const float* x    = (const float*)d_in[0];
    const float* W    = (const float*)d_in[1];
    const int*   esrc = (const int*)d_in[2];
    const int*   edst = (const int*)d_in[3];
    float* out = (float*)d_out;

    const int N = in_sizes[0] / HD;
    const int E = in_sizes[2];
    const int DEPTH = in_sizes[1] / (HD * 2 * HD);
    const int NBsc = (N + 1023) / 1024;    // 49 for N=50000 (must be <= 64)

    // ws: deg | bar | bsum | row_start | cursor | inv_deg | csr | hb0 | hb1 | neighb | Wb
    auto align256 = [](size_t v) { return (v + 255) & ~(size_t)255; };
    char* ws = (char*)d_ws;
    int*    deg       = (int*)ws;     ws += align256((size_t)(N + 8) * 4);
    int*    bar       = (int*)ws;     ws += align256(16 * 4);
    int*    bsum      = (int*)ws;     ws += align256(64 * 4);
    int*    row_start = (int*)ws;     ws += align256((size_t)(N + 1) * 4);
    int*    cursor    = (int*)ws;     ws += align256((size_t)N * 4);
    float*  inv_deg   = (float*)ws;   ws += align256((size_t)N * 4);
    int*    csr       = (int*)ws;     ws += align256((size_t)E * 4);
    ushort* hb0       = (ushort*)ws;  ws += align256((size_t)N * HD * 2);
    ushort* hb1       = (ushort*)ws;  ws += align256((size_t)N * HD * 2);
    ushort* neighb    = (ushort*)ws;  ws += align256((size_t)N * HD * 2);
    ushort* Wb        = (ushort*)ws;

    int xn4 = N * HD / 4;
    int wn4 = DEPTH * HD * 2 * HD / 4;
    int dn4 = (N + 8) / 4;
    int ptot = xn4 + wn4 + dn4 + 4;
    prep_kernel<<<(ptot + 255) / 256, 256, 0, stream>>>(
        (const float4*)x, (ushort4*)hb0, xn4,
        (const float4*)W, (ushort4*)Wb, wn4,
        (int4*)deg, dn4, (int4*)bar);

    build_kernel<<<NBLD, 256, 0, stream>>>(esrc, edst, deg, bsum, row_start,
                                           cursor, inv_deg, csr, bar, N, E, NBsc);

    ushort* hb_cur = hb0;
    ushort* hb_nxt = hb1;
    for (int k = 0; k < DEPTH; ++k) {
        int last = (k == DEPTH - 1) ? 1 : 0;
        agg_kernel<<<(N * 64 + 255) / 256, 256, 0, stream>>>(hb_cur, row_start, csr,
                                                             inv_deg, neighb, N);
        gemm_mfma_kernel<<<(N + 63) / 64, 256, 0, stream>>>(hb_cur, neighb,
                                                            Wb + (size_t)k * HD * 2 * HD,
                                                            out, hb_nxt, N, last);
        ushort* t = hb_cur; hb_cur = hb_nxt; hb_nxt = t;
    }
}

// Round 15
// 155.920 us; speedup vs baseline: 2.8103x; 2.8103x over previous
//
#include <hip/hip_runtime.h>

#define HD 64   // hidden dim D

typedef short  bf16x8 __attribute__((ext_vector_type(8)));
typedef float  f32x4  __attribute__((ext_vector_type(4)));

__device__ inline float bf2f(ushort u) {
    unsigned x = ((unsigned)u) << 16;
    return __builtin_bit_cast(float, x);
}
__device__ inline ushort f2bf(float f) {   // round-to-nearest-even
    unsigned u = __builtin_bit_cast(unsigned, f);
    u += 0x7fffu + ((u >> 16) & 1u);
    return (ushort)(u >> 16);
}

// ---- fused prep: f2bf(x) | f2bf(W) | zero deg ----
__global__ void prep_kernel(const float4* __restrict__ x, ushort4* __restrict__ hb, int xn4,
                            const float4* __restrict__ W, ushort4* __restrict__ Wb, int wn4,
                            int4* __restrict__ deg4, int dn4) {
    int i = blockIdx.x * blockDim.x + threadIdx.x;
    if (i < xn4) {
        float4 v = x[i];
        ushort4 o; o.x = f2bf(v.x); o.y = f2bf(v.y); o.z = f2bf(v.z); o.w = f2bf(v.w);
        hb[i] = o;
        return;
    }
    int j = i - xn4;
    if (j < wn4) {
        float4 v = W[j];
        ushort4 o; o.x = f2bf(v.x); o.y = f2bf(v.y); o.z = f2bf(v.z); o.w = f2bf(v.w);
        Wb[j] = o;
        return;
    }
    int k = j - wn4;
    if (k < dn4) deg4[k] = int4{0, 0, 0, 0};
}

// ---- degree histogram, dst-range partitioned (XCD-local atomic lines) ----
__global__ void deg_part_kernel(const int* __restrict__ dst, int* __restrict__ deg,
                                int E, int N) {
    const int g = blockIdx.x & 7;
    const int per = (N + 7) / 8;
    const int lo = g * per;
    const int hi = min(N, lo + per);
    const int nb = gridDim.x >> 3;
    const int b = blockIdx.x >> 3;
    for (int e = b * blockDim.x + threadIdx.x; e < E; e += nb * blockDim.x) {
        int d = dst[e];
        if (d >= lo && d < hi) atomicAdd(&deg[d], 1);
    }
}

// ---- per-block local exclusive scan of deg ----
__global__ __launch_bounds__(1024) void scanA_kernel(const int* __restrict__ deg,
                                                     int* __restrict__ excl,
                                                     int* __restrict__ bsum, int N) {
    const int tid = threadIdx.x, lane = tid & 63, wid = tid >> 6;
    const int i = blockIdx.x * 1024 + tid;
    int v = (i < N) ? deg[i] : 0;
    int s = v;
#pragma unroll
    for (int off = 1; off < 64; off <<= 1) {
        int t = __shfl_up(s, off, 64);
        if (lane >= off) s += t;
    }
    __shared__ int wtot[16], woff[16];
    if (lane == 63) wtot[wid] = s;
    __syncthreads();
    if (wid == 0 && lane < 16) {
        int t = wtot[lane];
        int ss = t;
#pragma unroll
        for (int off = 1; off < 16; off <<= 1) {
            int u = __shfl_up(ss, off, 64);
            if (lane >= off) ss += u;
        }
        woff[lane] = ss - t;
        if (lane == 15) bsum[blockIdx.x] = ss;
    }
    __syncthreads();
    if (i < N) excl[i] = woff[wid] + (s - v);
}

// ---- apply: scans bsum (NB<=64) in-wave per block ----
__global__ __launch_bounds__(1024) void scanC_kernel(const int* __restrict__ excl,
                                                     const int* __restrict__ bsum,
                                                     const int* __restrict__ deg,
                                                     int* __restrict__ row_start,
                                                     int* __restrict__ cursor,
                                                     float* __restrict__ inv_deg,
                                                     int N, int E, int NB) {
    __shared__ int boff_s;
    const int tid = threadIdx.x;
    if (tid < 64) {
        int lane = tid;
        int v = (lane < NB) ? bsum[lane] : 0;
        int s = v;
#pragma unroll
        for (int off = 1; off < 64; off <<= 1) {
            int t = __shfl_up(s, off, 64);
            if (lane >= off) s += t;
        }
        if (lane == (int)blockIdx.x) boff_s = s - v;
    }
    __syncthreads();
    const int boff = boff_s;
    int i = blockIdx.x * 1024 + tid;
    if (i < N) {
        int e = excl[i] + boff;
        row_start[i] = e;
        cursor[i] = e;
        int d = deg[i];
        inv_deg[i] = (d > 0) ? 1.0f / (float)d : 0.0f;
    }
    if (blockIdx.x == 0 && tid == 0) row_start[N] = E;
}

// ---- CSR fill, dst-range partitioned ----
__global__ void fill_part_kernel(const int* __restrict__ src, const int* __restrict__ dst,
                                 int* __restrict__ cursor, int* __restrict__ csr,
                                 int E, int N) {
    const int g = blockIdx.x & 7;
    const int per = (N + 7) / 8;
    const int lo = g * per;
    const int hi = min(N, lo + per);
    const int nb = gridDim.x >> 3;
    const int b = blockIdx.x >> 3;
    for (int e = b * blockDim.x + threadIdx.x; e < E; e += nb * blockDim.x) {
        int d = dst[e];
        if (d >= lo && d < hi) {
            int p = atomicAdd(&cursor[d], 1);
            csr[p] = src[e];
        }
    }
}

// ---- aggregate: wave per node, 4 lane-groups x 16 lanes, ushort4/lane;
// 16-neighbor inner step = 4 loads in flight per lane ----
__global__ __launch_bounds__(256, 8) void agg_kernel(
    const ushort* __restrict__ hb, const int* __restrict__ row_start,
    const int* __restrict__ csr, const float* __restrict__ inv_deg,
    ushort* __restrict__ neighb, int N) {
    const int wv = (blockIdx.x * blockDim.x + threadIdx.x) >> 6;
    const int lane = threadIdx.x & 63;
    if (wv >= N) return;
    const int rs = row_start[wv];
    const int re = row_start[wv + 1];
    const int grp = lane >> 4;
    const int sub = (lane & 15) << 2;

    float a0 = 0.f, a1 = 0.f, a2 = 0.f, a3 = 0.f;
    float b0 = 0.f, b1 = 0.f, b2 = 0.f, b3 = 0.f;
    float c0 = 0.f, c1 = 0.f, c2 = 0.f, c3 = 0.f;
    float d0 = 0.f, d1 = 0.f, d2 = 0.f, d3 = 0.f;
    int j = rs;
    while (j < re) {
        int take = re - j;
        if (take > 64) take = 64;
        int idx = (lane < take) ? csr[j + lane] : 0;
        int i = 0;
        for (; i + 16 <= take; i += 16) {
            int s0 = __shfl(idx, i + grp, 64);
            int s1 = __shfl(idx, i + 4 + grp, 64);
            int s2 = __shfl(idx, i + 8 + grp, 64);
            int s3 = __shfl(idx, i + 12 + grp, 64);
            ushort4 v0 = *(const ushort4*)&hb[(s0 << 6) + sub];
            ushort4 v1 = *(const ushort4*)&hb[(s1 << 6) + sub];
            ushort4 v2 = *(const ushort4*)&hb[(s2 << 6) + sub];
            ushort4 v3 = *(const ushort4*)&hb[(s3 << 6) + sub];
            a0 += bf2f(v0.x); a1 += bf2f(v0.y); a2 += bf2f(v0.z); a3 += bf2f(v0.w);
            b0 += bf2f(v1.x); b1 += bf2f(v1.y); b2 += bf2f(v1.z); b3 += bf2f(v1.w);
            c0 += bf2f(v2.x); c1 += bf2f(v2.y); c2 += bf2f(v2.z); c3 += bf2f(v2.w);
            d0 += bf2f(v3.x); d1 += bf2f(v3.y); d2 += bf2f(v3.z); d3 += bf2f(v3.w);
        }
        for (; i + 8 <= take; i += 8) {
            int s0 = __shfl(idx, i + grp, 64);
            int s1 = __shfl(idx, i + 4 + grp, 64);
            ushort4 v0 = *(const ushort4*)&hb[(s0 << 6) + sub];
            ushort4 v1 = *(const ushort4*)&hb[(s1 << 6) + sub];
            a0 += bf2f(v0.x); a1 += bf2f(v0.y); a2 += bf2f(v0.z); a3 += bf2f(v0.w);
            b0 += bf2f(v1.x); b1 += bf2f(v1.y); b2 += bf2f(v1.z); b3 += bf2f(v1.w);
        }
        for (; i < take; i += 4) {
            int p = i + grp;
            int s = __shfl(idx, p < take ? p : 0, 64);
            if (p < take) {
                ushort4 v = *(const ushort4*)&hb[(s << 6) + sub];
                a0 += bf2f(v.x); a1 += bf2f(v.y); a2 += bf2f(v.z); a3 += bf2f(v.w);
            }
        }
        j += take;
    }
    a0 += b0 + c0 + d0; a1 += b1 + c1 + d1;
    a2 += b2 + c2 + d2; a3 += b3 + c3 + d3;
    a0 += __shfl_xor(a0, 16, 64); a0 += __shfl_xor(a0, 32, 64);
    a1 += __shfl_xor(a1, 16, 64); a1 += __shfl_xor(a1, 32, 64);
    a2 += __shfl_xor(a2, 16, 64); a2 += __shfl_xor(a2, 32, 64);
    a3 += __shfl_xor(a3, 16, 64); a3 += __shfl_xor(a3, 32, 64);
    if (grp == 0) {
        float inv = inv_deg[wv];
        ushort4 o;
        o.x = f2bf(a0 * inv); o.y = f2bf(a1 * inv);
        o.z = f2bf(a2 * inv); o.w = f2bf(a3 * inv);
        *(ushort4*)&neighb[(wv << 6) + sub] = o;
    }
}

// ---- MFMA GEMM + relu + L2-norm (round-9 proven) ----
__global__ __launch_bounds__(256) void gemm_mfma_kernel(
    const ushort* __restrict__ hb, const ushort* __restrict__ nbf,
    const ushort* __restrict__ Wb, float* __restrict__ out,
    ushort* __restrict__ hb_out, int N, int last) {
    const int lane = threadIdx.x & 63;
    const int w = threadIdx.x >> 6;
    const int base = blockIdx.x * 64 + w * 16;
    const int m = lane & 15;
    const int kq = lane >> 4;
    int anode = base + m;
    if (anode > N - 1) anode = N - 1;
    const long long arow = (long long)anode * HD;

    f32x4 acc[4] = {{0.f,0.f,0.f,0.f},{0.f,0.f,0.f,0.f},{0.f,0.f,0.f,0.f},{0.f,0.f,0.f,0.f}};
#pragma unroll
    for (int kk = 0; kk < 4; ++kk) {
        const ushort* ap = (kk < 2 ? hb : nbf) + arow + (kk & 1) * 32 + kq * 8;
        bf16x8 a = *(const bf16x8*)ap;
        const ushort* bp = Wb + (long long)m * 128 + kk * 32 + kq * 8;
#pragma unroll
        for (int t = 0; t < 4; ++t) {
            bf16x8 b = *(const bf16x8*)(bp + (long long)t * 16 * 128);
            acc[t] = __builtin_amdgcn_mfma_f32_16x16x32_bf16(a, b, acc[t], 0, 0, 0);
        }
    }

    float sq[4] = {0.f, 0.f, 0.f, 0.f};
#pragma unroll
    for (int t = 0; t < 4; ++t)
#pragma unroll
        for (int r = 0; r < 4; ++r) {
            float v = fmaxf(acc[t][r], 0.f);
            acc[t][r] = v;
            sq[r] += v * v;
        }
#pragma unroll
    for (int off = 1; off < 16; off <<= 1)
#pragma unroll
        for (int r = 0; r < 4; ++r) sq[r] += __shfl_xor(sq[r], off, 64);

    float scl[4];
#pragma unroll
    for (int r = 0; r < 4; ++r) scl[r] = 1.f / fmaxf(sqrtf(sq[r]), 1e-12f);

    if (last) {
#pragma unroll
        for (int r = 0; r < 4; ++r) {
            int node = base + kq * 4 + r;
            if (node < N) {
#pragma unroll
                for (int t = 0; t < 4; ++t)
                    out[(long long)node * HD + t * 16 + m] = acc[t][r] * scl[r];
            }
        }
    } else {
#pragma unroll
        for (int r = 0; r < 4; ++r) {
            int node = base + kq * 4 + r;
            if (node < N) {
#pragma unroll
                for (int t = 0; t < 4; ++t)
                    hb_out[(long long)node * HD + t * 16 + m] = f2bf(acc[t][r] * scl[r]);
            }
        }
    }
}

extern "C" void kernel_launch(void* const* d_in, const int* in_sizes, int n_in,
                              void* d_out, int out_size, void* d_ws, size_t ws_size,
                              hipStream_t stream) {
    const float* x    = (const float*)d_in[0];
    const float* W    = (const float*)d_in[1];
    const int*   esrc = (const int*)d_in[2];
    const int*   edst = (const int*)d_in[3];
    float* out = (float*)d_out;

    const int N = in_sizes[0] / HD;
    const int E = in_sizes[2];
    const int DEPTH = in_sizes[1] / (HD * 2 * HD);
    const int NB = (N + 1023) / 1024;

    // ws: deg | excl | bsum | row_start | cursor | inv_deg | csr | hb0 | hb1 | neighb | Wb
    auto align256 = [](size_t v) { return (v + 255) & ~(size_t)255; };
    char* ws = (char*)d_ws;
    int*    deg       = (int*)ws;     ws += align256((size_t)(N + 8) * 4);
    int*    excl      = (int*)ws;     ws += align256((size_t)N * 4);
    int*    bsum      = (int*)ws;     ws += align256(64 * 4);
    int*    row_start = (int*)ws;     ws += align256((size_t)(N + 1) * 4);
    int*    cursor    = (int*)ws;     ws += align256((size_t)N * 4);
    float*  inv_deg   = (float*)ws;   ws += align256((size_t)N * 4);
    int*    csr       = (int*)ws;     ws += align256((size_t)E * 4);
    ushort* hb0       = (ushort*)ws;  ws += align256((size_t)N * HD * 2);
    ushort* hb1       = (ushort*)ws;  ws += align256((size_t)N * HD * 2);
    ushort* neighb    = (ushort*)ws;  ws += align256((size_t)N * HD * 2);
    ushort* Wb        = (ushort*)ws;

    int xn4 = N * HD / 4;
    int wn4 = DEPTH * HD * 2 * HD / 4;
    int dn4 = (N + 8) / 4;
    int ptot = xn4 + wn4 + dn4;
    prep_kernel<<<(ptot + 255) / 256, 256, 0, stream>>>(
        (const float4*)x, (ushort4*)hb0, xn4,
        (const float4*)W, (ushort4*)Wb, wn4,
        (int4*)deg, dn4);

    deg_part_kernel<<<2048, 256, 0, stream>>>(edst, deg, E, N);
    scanA_kernel<<<NB, 1024, 0, stream>>>(deg, excl, bsum, N);
    scanC_kernel<<<NB, 1024, 0, stream>>>(excl, bsum, deg, row_start, cursor, inv_deg, N, E, NB);
    fill_part_kernel<<<2048, 256, 0, stream>>>(esrc, edst, cursor, csr, E, N);

    ushort* hb_cur = hb0;
    ushort* hb_nxt = hb1;
    for (int k = 0; k < DEPTH; ++k) {
        int last = (k == DEPTH - 1) ? 1 : 0;
        agg_kernel<<<(N * 64 + 255) / 256, 256, 0, stream>>>(hb_cur, row_start, csr,
                                                             inv_deg, neighb, N);
        gemm_mfma_kernel<<<(N + 63) / 64, 256, 0, stream>>>(hb_cur, neighb,
                                                            Wb + (size_t)k * HD * 2 * HD,
                                                            out, hb_nxt, N, last);
        ushort* t = hb_cur; hb_cur = hb_nxt; hb_nxt = t;
    }
}